// Round 1
// baseline (317.546 us; speedup 1.0000x reference)
//
#include <hip/hip_runtime.h>
#include <hip/hip_bf16.h>

typedef __hip_bfloat16 bf16;
typedef __attribute__((ext_vector_type(8))) short short8;
typedef __attribute__((ext_vector_type(4))) short short4v;
typedef __attribute__((ext_vector_type(4))) float f32x4;
typedef __attribute__((ext_vector_type(4))) float float4v;

static __device__ inline short f2bf(float f){
  __hip_bfloat16 h = __float2bfloat16(f);
  return *reinterpret_cast<short*>(&h);
}

static __device__ inline short8 load8(const float* p){
  float4v a = *reinterpret_cast<const float4v*>(p);
  float4v b = *reinterpret_cast<const float4v*>(p + 4);
  short8 r;
  r[0]=f2bf(a[0]); r[1]=f2bf(a[1]); r[2]=f2bf(a[2]); r[3]=f2bf(a[3]);
  r[4]=f2bf(b[0]); r[5]=f2bf(b[1]); r[6]=f2bf(b[2]); r[7]=f2bf(b[3]);
  return r;
}
static __device__ inline short8 load8(const bf16* p){
  return *reinterpret_cast<const short8*>(p);
}

// C[M,N] = A[M,K] @ B[N,K]^T + bias[N]; A,B cast to bf16 during staging.
template<typename TA, typename TB>
__global__ __launch_bounds__(256) void gemm_bt_kernel(
    float* __restrict__ C, const TA* __restrict__ A, const TB* __restrict__ B,
    const float* __restrict__ bias, int M, int N, int K)
{
  constexpr int BK = 32, LDT = 40;  // +8 bf16 pad -> 80B row stride, 16B aligned, 2-way banks (free)
  __shared__ short As[128 * LDT];
  __shared__ short Bs[128 * LDT];
  const int n0 = blockIdx.x * 128, m0 = blockIdx.y * 128;
  const int tid = threadIdx.x;
  const int w = tid >> 6, lane = tid & 63;
  const int wm = w >> 1, wn = w & 1;
  const int lr = lane & 15, lk = (lane >> 4) * 8;
  f32x4 acc[4][4] = {};
  for (int k0 = 0; k0 < K; k0 += BK){
    __syncthreads();
    {
      const int r = tid >> 2, c8 = (tid & 3) * 8;
      *reinterpret_cast<short8*>(&As[ r      * LDT + c8]) = load8(A + (size_t)(m0 + r     ) * K + k0 + c8);
      *reinterpret_cast<short8*>(&As[(r + 64)* LDT + c8]) = load8(A + (size_t)(m0 + r + 64) * K + k0 + c8);
      *reinterpret_cast<short8*>(&Bs[ r      * LDT + c8]) = load8(B + (size_t)(n0 + r     ) * K + k0 + c8);
      *reinterpret_cast<short8*>(&Bs[(r + 64)* LDT + c8]) = load8(B + (size_t)(n0 + r + 64) * K + k0 + c8);
    }
    __syncthreads();
    short8 af[4], bfm[4];
    #pragma unroll
    for (int mt = 0; mt < 4; mt++)
      af[mt] = *reinterpret_cast<short8*>(&As[(wm*64 + mt*16 + lr) * LDT + lk]);
    #pragma unroll
    for (int nt = 0; nt < 4; nt++)
      bfm[nt] = *reinterpret_cast<short8*>(&Bs[(wn*64 + nt*16 + lr) * LDT + lk]);
    #pragma unroll
    for (int mt = 0; mt < 4; mt++)
      #pragma unroll
      for (int nt = 0; nt < 4; nt++)
        acc[mt][nt] = __builtin_amdgcn_mfma_f32_16x16x32_bf16(af[mt], bfm[nt], acc[mt][nt], 0, 0, 0);
  }
  const int lg = lane >> 4;
  #pragma unroll
  for (int mt = 0; mt < 4; mt++){
    #pragma unroll
    for (int nt = 0; nt < 4; nt++){
      const int col = n0 + wn*64 + nt*16 + lr;
      const float bv = bias[col];
      const int rbase = m0 + wm*64 + mt*16 + lg*4;
      #pragma unroll
      for (int i = 0; i < 4; i++)
        C[(size_t)(rbase + i) * N + col] = acc[mt][nt][i] + bv;
    }
  }
}

// RoPE + layout change: src fp32 [B*2048, nh*64] -> dst bf16 [B*nh, 2048, 64]
__global__ void rope_kernel(bf16* __restrict__ dst, const float* __restrict__ src, int nh)
{
  const int idx = blockIdx.x * 256 + threadIdx.x;   // B*2048*nh*32 threads
  const int d  = idx & 31;
  const int hh = (idx >> 5) % nh;
  const int row = idx / (32 * nh);                  // b*2048 + s
  const int s = row & 2047, b = row >> 11;
  const float* p = src + (size_t)row * (nh * 64) + hh * 64 + d;
  const float x1 = p[0], x2 = p[32];
  // inv_freq = 10000^(-d/32) = 2^(-d * log2(10000)/32)
  const float ang = (float)s * exp2f(-0.41524101186092030f * (float)d);
  float sn, cs;
  sincosf(ang, &sn, &cs);
  const size_t o = ((size_t)(b * nh + hh) * 2048 + s) * 64 + d;
  dst[o]      = __float2bfloat16(x1 * cs - x2 * sn);
  dst[o + 32] = __float2bfloat16(x2 * cs + x1 * sn);
}

// V: fp32 [B*2048, 4*64] -> bf16 [B*4, 2048, 64]
__global__ void convv_kernel(bf16* __restrict__ dst, const float* __restrict__ src)
{
  const int idx = blockIdx.x * 256 + threadIdx.x;   // 4096*256/4 threads
  const int d4 = idx & 15;
  const int kv = (idx >> 4) & 3;
  const int row = idx >> 6;
  const int s = row & 2047, b = row >> 11;
  float4v v = *reinterpret_cast<const float4v*>(src + (size_t)row * 256 + kv * 64 + d4 * 4);
  short4v r; r[0]=f2bf(v[0]); r[1]=f2bf(v[1]); r[2]=f2bf(v[2]); r[3]=f2bf(v[3]);
  *reinterpret_cast<short4v*>(reinterpret_cast<short*>(dst) + ((size_t)(b*4+kv)*2048 + s)*64 + d4*4) = r;
}

// Flash attention: grid (S/64, B*H); 4 waves, 16 q-rows/wave, KV tiles of 64.
__global__ __launch_bounds__(256) void attn_kernel(
    bf16* __restrict__ ctx, const bf16* __restrict__ Qa,
    const bf16* __restrict__ Ka, const bf16* __restrict__ Va)
{
  constexpr int SLEN = 2048, DK = 64, KVB = 64, LD = 72;  // 144B rows: 16B aligned, 2-way banks
  __shared__ short Klds[KVB * LD];
  __shared__ short Vt[DK * LD];       // V transposed: Vt[d][kv]
  __shared__ short Plds[4 * 16 * LD]; // per-wave P scratch
  const int bh = blockIdx.y, b = bh >> 4, h = bh & 15, kvh = h >> 2;
  const int q0 = blockIdx.x * 64;
  const int tid = threadIdx.x, w = tid >> 6, lane = tid & 63;
  const int lr = lane & 15, lg = lane >> 4;
  const bf16* Qbase = Qa + (size_t)bh * SLEN * DK;
  const bf16* Kbase = Ka + (size_t)(b * 4 + kvh) * SLEN * DK;
  const bf16* Vbase = Va + (size_t)(b * 4 + kvh) * SLEN * DK;
  short8 qf[2];
  {
    const int qr = q0 + w * 16 + lr;
    qf[0] = *reinterpret_cast<const short8*>(Qbase + (size_t)qr * DK + lg * 8);
    qf[1] = *reinterpret_cast<const short8*>(Qbase + (size_t)qr * DK + 32 + lg * 8);
  }
  float mrow[4] = {-1e30f, -1e30f, -1e30f, -1e30f};
  float lsum[4] = {0.f, 0.f, 0.f, 0.f};
  f32x4 o[4] = {};
  const int sr = tid >> 3, sc8 = (tid & 7) * 8;
  for (int kt = 0; kt < SLEN; kt += KVB){
    __syncthreads();
    #pragma unroll
    for (int it = 0; it < 2; it++){
      const int row = sr + it * 32;
      short8 kvv = *reinterpret_cast<const short8*>(Kbase + (size_t)(kt + row) * DK + sc8);
      *reinterpret_cast<short8*>(&Klds[row * LD + sc8]) = kvv;
      short8 vv = *reinterpret_cast<const short8*>(Vbase + (size_t)(kt + row) * DK + sc8);
      #pragma unroll
      for (int j = 0; j < 8; j++) Vt[(sc8 + j) * LD + row] = vv[j];
    }
    __syncthreads();
    // S = Q K^T
    f32x4 st[4] = {};
    #pragma unroll
    for (int t = 0; t < 4; t++){
      #pragma unroll
      for (int kk = 0; kk < 2; kk++){
        short8 kf = *reinterpret_cast<const short8*>(&Klds[(t*16 + lr) * LD + kk*32 + lg*8]);
        st[t] = __builtin_amdgcn_mfma_f32_16x16x32_bf16(qf[kk], kf, st[t], 0, 0, 0);
      }
    }
    #pragma unroll
    for (int t = 0; t < 4; t++)
      #pragma unroll
      for (int i = 0; i < 4; i++)
        st[t][i] *= 0.125f;
    // online softmax (rows owned: lg*4+i; reduce over 16 lanes = 16 k-cols)
    float nm[4], alpha[4];
    #pragma unroll
    for (int i = 0; i < 4; i++){
      float mx = fmaxf(fmaxf(st[0][i], st[1][i]), fmaxf(st[2][i], st[3][i]));
      #pragma unroll
      for (int dd = 1; dd < 16; dd <<= 1) mx = fmaxf(mx, __shfl_xor(mx, dd));
      nm[i] = fmaxf(mrow[i], mx);
      alpha[i] = __expf(mrow[i] - nm[i]);
      mrow[i] = nm[i];
    }
    #pragma unroll
    for (int t = 0; t < 4; t++)
      #pragma unroll
      for (int i = 0; i < 4; i++)
        st[t][i] = __expf(st[t][i] - nm[i]);
    #pragma unroll
    for (int i = 0; i < 4; i++){
      float s = st[0][i] + st[1][i] + st[2][i] + st[3][i];
      #pragma unroll
      for (int dd = 1; dd < 16; dd <<= 1) s += __shfl_xor(s, dd);
      lsum[i] = lsum[i] * alpha[i] + s;
    }
    #pragma unroll
    for (int db = 0; db < 4; db++)
      #pragma unroll
      for (int i = 0; i < 4; i++)
        o[db][i] *= alpha[i];
    // P -> LDS (transpose to A-fragment layout), then PV
    short* Pw = &Plds[w * 16 * LD];
    #pragma unroll
    for (int t = 0; t < 4; t++)
      #pragma unroll
      for (int i = 0; i < 4; i++)
        Pw[(lg*4 + i) * LD + t*16 + lr] = f2bf(st[t][i]);
    asm volatile("s_waitcnt lgkmcnt(0)" ::: "memory");
    short8 pf0 = *reinterpret_cast<const short8*>(&Pw[lr * LD + lg * 8]);
    short8 pf1 = *reinterpret_cast<const short8*>(&Pw[lr * LD + 32 + lg * 8]);
    #pragma unroll
    for (int db = 0; db < 4; db++){
      short8 v0 = *reinterpret_cast<const short8*>(&Vt[(db*16 + lr) * LD + lg * 8]);
      short8 v1 = *reinterpret_cast<const short8*>(&Vt[(db*16 + lr) * LD + 32 + lg * 8]);
      o[db] = __builtin_amdgcn_mfma_f32_16x16x32_bf16(pf0, v0, o[db], 0, 0, 0);
      o[db] = __builtin_amdgcn_mfma_f32_16x16x32_bf16(pf1, v1, o[db], 0, 0, 0);
    }
  }
  // epilogue: ctx bf16 in [B, S, H*64] layout for the final GEMM
  #pragma unroll
  for (int db = 0; db < 4; db++){
    #pragma unroll
    for (int i = 0; i < 4; i++){
      const int qr = q0 + w * 16 + lg * 4 + i;
      const float val = o[db][i] / lsum[i];
      ctx[(size_t)(b * 2048 + qr) * 1024 + h * 64 + db * 16 + lr] = __float2bfloat16(val);
    }
  }
}

extern "C" void kernel_launch(void* const* d_in, const int* in_sizes, int n_in,
                              void* d_out, int out_size, void* d_ws, size_t ws_size,
                              hipStream_t stream)
{
  const float* query = (const float*)d_in[0];
  const float* key   = (const float*)d_in[1];
  const float* value = (const float*)d_in[2];
  const float* Wq = (const float*)d_in[3];
  const float* bq = (const float*)d_in[4];
  const float* Wk = (const float*)d_in[5];
  const float* bk = (const float*)d_in[6];
  const float* Wv = (const float*)d_in[7];
  const float* bv = (const float*)d_in[8];
  const float* Wo = (const float*)d_in[9];
  const float* bo = (const float*)d_in[10];
  float* out = (float*)d_out;

  char* ws = (char*)d_ws;
  size_t off = 0;
  float* Qp = (float*)(ws + off); off += (size_t)4096 * 1024 * 4;  // Q proj fp32
  float* Kp = (float*)(ws + off); off += (size_t)4096 * 256 * 4;   // K proj fp32
  float* Vp = (float*)(ws + off); off += (size_t)4096 * 256 * 4;   // V proj fp32
  bf16*  Qa = (bf16*)(ws + off);  off += (size_t)4096 * 1024 * 2;  // roped Q bf16 [B*H,S,64]
  bf16*  Ka = (bf16*)(ws + off);  off += (size_t)8 * 2048 * 64 * 2; // roped K bf16 [B*KV,S,64]
  bf16*  Va = (bf16*)(ws + off);  off += (size_t)8 * 2048 * 64 * 2; // V bf16 [B*KV,S,64]
  bf16* ctx = (bf16*)(ws + off);  off += (size_t)4096 * 1024 * 2;  // context bf16 [B,S,H*64]

  gemm_bt_kernel<float, float><<<dim3(8, 32), 256, 0, stream>>>(Qp, query, Wq, bq, 4096, 1024, 1024);
  gemm_bt_kernel<float, float><<<dim3(2, 32), 256, 0, stream>>>(Kp, key,   Wk, bk, 4096, 256, 1024);
  gemm_bt_kernel<float, float><<<dim3(2, 32), 256, 0, stream>>>(Vp, value, Wv, bv, 4096, 256, 1024);
  rope_kernel<<<8192, 256, 0, stream>>>(Qa, Qp, 16);
  rope_kernel<<<2048, 256, 0, stream>>>(Ka, Kp, 4);
  convv_kernel<<<1024, 256, 0, stream>>>(Va, Vp);
  attn_kernel<<<dim3(32, 32), 256, 0, stream>>>(ctx, Qa, Ka, Va);
  gemm_bt_kernel<bf16, float><<<dim3(8, 32), 256, 0, stream>>>(out, ctx, Wo, bo, 4096, 1024, 1024);
}

// Round 2
// 188.231 us; speedup vs baseline: 1.6870x; 1.6870x over previous
//
#include <hip/hip_runtime.h>
#include <hip/hip_bf16.h>

typedef __hip_bfloat16 bf16;
typedef __attribute__((ext_vector_type(8))) short short8;
typedef __attribute__((ext_vector_type(4))) short short4v;
typedef __attribute__((ext_vector_type(4))) float f32x4;
typedef __attribute__((ext_vector_type(4))) float float4v;

static __device__ inline short f2bf(float f){
  __hip_bfloat16 h = __float2bfloat16(f);
  return *reinterpret_cast<short*>(&h);
}

static __device__ inline short8 load8(const float* p){
  float4v a = *reinterpret_cast<const float4v*>(p);
  float4v b = *reinterpret_cast<const float4v*>(p + 4);
  short8 r;
  r[0]=f2bf(a[0]); r[1]=f2bf(a[1]); r[2]=f2bf(a[2]); r[3]=f2bf(a[3]);
  r[4]=f2bf(b[0]); r[5]=f2bf(b[1]); r[6]=f2bf(b[2]); r[7]=f2bf(b[3]);
  return r;
}
static __device__ inline short8 load8(const bf16* p){
  return *reinterpret_cast<const short8*>(p);
}

// cos/sin table: tab[s*32+d] = {cos, sin} of s * 10000^(-d/32)
__global__ void rope_table_kernel(float* __restrict__ tab){
  const int idx = blockIdx.x * 256 + threadIdx.x;   // 2048*32
  const int d = idx & 31, s = idx >> 5;
  const float ang = (float)s * exp2f(-0.41524101186092030f * (float)d);
  float sn, cs;
  sincosf(ang, &sn, &cs);
  tab[idx*2] = cs; tab[idx*2+1] = sn;
}

// Shared GEMM body: C = A[M,K] @ B[N,K]^T + bias, epilogue by MODE.
// MODE 0: fp32 C[M,N].  MODE 1: rope -> Qa bf16 [B*16,2048,64].
// MODE 2: rope -> Ka bf16 [B*4,2048,64].  MODE 3: V^T bf16 [B*4,64,2048].
template<int MODE, typename TA>
__device__ __forceinline__ void gemm_bt_body(
    short* As, short* Bs, void* __restrict__ Cout,
    const TA* __restrict__ A, const float* __restrict__ B,
    const float* __restrict__ bias, const float* __restrict__ tab,
    int M, int N, int K)
{
  constexpr int BK = 32, LDT = 40;  // 80B rows: 16B aligned, 2-way banks (free)
  const int n0 = blockIdx.x * 128, m0 = blockIdx.y * 128;
  const int tid = threadIdx.x;
  const int w = tid >> 6, lane = tid & 63;
  const int wm = w >> 1, wn = w & 1;
  const int lr = lane & 15, lk = (lane >> 4) * 8;
  f32x4 acc[4][4] = {};
  for (int k0 = 0; k0 < K; k0 += BK){
    __syncthreads();
    {
      const int r = tid >> 2, c8 = (tid & 3) * 8;
      *reinterpret_cast<short8*>(&As[ r      * LDT + c8]) = load8(A + (size_t)(m0 + r     ) * K + k0 + c8);
      *reinterpret_cast<short8*>(&As[(r + 64)* LDT + c8]) = load8(A + (size_t)(m0 + r + 64) * K + k0 + c8);
      *reinterpret_cast<short8*>(&Bs[ r      * LDT + c8]) = load8(B + (size_t)(n0 + r     ) * K + k0 + c8);
      *reinterpret_cast<short8*>(&Bs[(r + 64)* LDT + c8]) = load8(B + (size_t)(n0 + r + 64) * K + k0 + c8);
    }
    __syncthreads();
    short8 af[4], bfm[4];
    #pragma unroll
    for (int mt = 0; mt < 4; mt++)
      af[mt] = *reinterpret_cast<short8*>(&As[(wm*64 + mt*16 + lr) * LDT + lk]);
    #pragma unroll
    for (int nt = 0; nt < 4; nt++)
      bfm[nt] = *reinterpret_cast<short8*>(&Bs[(wn*64 + nt*16 + lr) * LDT + lk]);
    #pragma unroll
    for (int mt = 0; mt < 4; mt++)
      #pragma unroll
      for (int nt = 0; nt < 4; nt++)
        acc[mt][nt] = __builtin_amdgcn_mfma_f32_16x16x32_bf16(af[mt], bfm[nt], acc[mt][nt], 0, 0, 0);
  }
  const int lg = lane >> 4;
  if constexpr (MODE == 0){
    float* C = (float*)Cout;
    #pragma unroll
    for (int mt = 0; mt < 4; mt++){
      #pragma unroll
      for (int nt = 0; nt < 4; nt++){
        const int col = n0 + wn*64 + nt*16 + lr;
        const float bv = bias[col];
        const int rbase = m0 + wm*64 + mt*16 + lg*4;
        #pragma unroll
        for (int i = 0; i < 4; i++)
          C[(size_t)(rbase + i) * N + col] = acc[mt][nt][i] + bv;
      }
    }
  } else if constexpr (MODE == 1 || MODE == 2){
    bf16* dst = (bf16*)Cout;
    constexpr int NH = (MODE == 1) ? 16 : 4;
    #pragma unroll
    for (int mt = 0; mt < 4; mt++){
      #pragma unroll
      for (int nt = 0; nt < 2; nt++){
        const int col = n0 + wn*64 + nt*16 + lr;
        const int d = col & 63;        // 0..31
        const int hh = col >> 6;
        const float b1 = bias[col], b2 = bias[col + 32];
        #pragma unroll
        for (int i = 0; i < 4; i++){
          const int m = m0 + wm*64 + mt*16 + lg*4 + i;
          const int s = m & 2047, bb = m >> 11;
          const float cs = tab[(s*32 + d)*2], sn = tab[(s*32 + d)*2 + 1];
          const float x1 = acc[mt][nt][i] + b1;
          const float x2 = acc[mt][nt+2][i] + b2;
          const size_t o = ((size_t)(bb*NH + hh) * 2048 + s) * 64 + d;
          dst[o]      = __float2bfloat16(x1*cs - x2*sn);
          dst[o + 32] = __float2bfloat16(x2*cs + x1*sn);
        }
      }
    }
  } else {  // MODE 3: V^T
    bf16* dst = (bf16*)Cout;
    #pragma unroll
    for (int mt = 0; mt < 4; mt++){
      #pragma unroll
      for (int nt = 0; nt < 4; nt++){
        const int col = n0 + wn*64 + nt*16 + lr;
        const int kv = col >> 6, d = col & 63;
        const float bv = bias[col];
        #pragma unroll
        for (int i = 0; i < 4; i++){
          const int m = m0 + wm*64 + mt*16 + lg*4 + i;
          const int s = m & 2047, bb = m >> 11;
          dst[((size_t)(bb*4 + kv) * 64 + d) * 2048 + s] = __float2bfloat16(acc[mt][nt][i] + bv);
        }
      }
    }
  }
}

__global__ __launch_bounds__(256) void gemm_q_kernel(
    bf16* Qa, const float* A, const float* B, const float* bias, const float* tab){
  __shared__ short As[128*40], Bs[128*40];
  gemm_bt_body<1, float>(As, Bs, Qa, A, B, bias, tab, 4096, 1024, 1024);
}
__global__ __launch_bounds__(256) void gemm_kv_kernel(
    bf16* Ka, bf16* Va, const float* key, const float* value,
    const float* Wk, const float* bk, const float* Wv, const float* bv,
    const float* tab){
  __shared__ short As[128*40], Bs[128*40];
  if (blockIdx.z == 0)
    gemm_bt_body<2, float>(As, Bs, Ka, key, Wk, bk, tab, 4096, 256, 1024);
  else
    gemm_bt_body<3, float>(As, Bs, Va, value, Wv, bv, tab, 4096, 256, 1024);
}
__global__ __launch_bounds__(256) void gemm_out_kernel(
    float* C, const bf16* A, const float* B, const float* bias){
  __shared__ short As[128*40], Bs[128*40];
  gemm_bt_body<0, bf16>(As, Bs, C, A, B, bias, nullptr, 4096, 1024, 1024);
}

// Flash attention: grid (2048/128, B*H); 4 waves, 32 q-rows/wave, KV tiles of 64.
// Swapped QK^T (S^T = K x Q) so P writes/reads to LDS are vectorized.
__global__ __launch_bounds__(256) void attn_kernel(
    bf16* __restrict__ ctx, const bf16* __restrict__ Qa,
    const bf16* __restrict__ Ka, const bf16* __restrict__ Vt)
{
  constexpr int DK = 64, KVB = 64, LD = 72, LDP = 72;
  __shared__ short Klds[KVB * LD];    // [kv][d]
  __shared__ short Vlds[DK * LD];     // [d][kv]  (staged from pre-transposed V)
  __shared__ short Plds[4 * 32 * LDP];// per-wave P[q][kv]
  const int bh = blockIdx.y, b = bh >> 4, h = bh & 15, kvh = h >> 2;
  const int q0 = blockIdx.x * 128;
  const int tid = threadIdx.x, w = tid >> 6, lane = tid & 63;
  const int lr = lane & 15, lg = lane >> 4;
  const bf16* Qbase = Qa + (size_t)bh * 2048 * DK;
  const bf16* Kbase = Ka + (size_t)(b*4 + kvh) * 2048 * DK;
  const bf16* Vbase = Vt + (size_t)(b*4 + kvh) * DK * 2048;

  short8 qf[2][2];
  #pragma unroll
  for (int qt = 0; qt < 2; qt++)
    #pragma unroll
    for (int kk = 0; kk < 2; kk++)
      qf[qt][kk] = *reinterpret_cast<const short8*>(
          Qbase + (size_t)(q0 + w*32 + qt*16 + lr) * DK + kk*32 + lg*8);

  float mrow[2] = {-1e30f, -1e30f}, lsum[2] = {0.f, 0.f};
  f32x4 o[2][4] = {};

  const int srow = tid >> 2, scol = (tid & 3) * 16;
  short8 kreg[2], vreg[2];
  auto loadKV = [&](int kt){
    const bf16* p = Kbase + (size_t)(kt + srow) * DK + scol;
    kreg[0] = *reinterpret_cast<const short8*>(p);
    kreg[1] = *reinterpret_cast<const short8*>(p + 8);
    const bf16* q = Vbase + (size_t)srow * 2048 + kt + scol;
    vreg[0] = *reinterpret_cast<const short8*>(q);
    vreg[1] = *reinterpret_cast<const short8*>(q + 8);
  };
  loadKV(0);

  short* Pw = &Plds[w * 32 * LDP];
  for (int kt = 0; kt < 2048; kt += KVB){
    __syncthreads();   // previous tile's compute done
    *reinterpret_cast<short8*>(&Klds[srow*LD + scol])     = kreg[0];
    *reinterpret_cast<short8*>(&Klds[srow*LD + scol + 8]) = kreg[1];
    *reinterpret_cast<short8*>(&Vlds[srow*LD + scol])     = vreg[0];
    *reinterpret_cast<short8*>(&Vlds[srow*LD + scol + 8]) = vreg[1];
    __syncthreads();   // tile visible
    if (kt + KVB < 2048) loadKV(kt + KVB);  // prefetch overlaps compute

    // S^T = K x Q : st[mt][qt], lane holds S^T[kv=mt*16+lg*4+i][q=qt*16+lr]
    f32x4 st[4][2] = {};
    #pragma unroll
    for (int mt = 0; mt < 4; mt++){
      #pragma unroll
      for (int kk = 0; kk < 2; kk++){
        short8 kf = *reinterpret_cast<const short8*>(&Klds[(mt*16 + lr)*LD + kk*32 + lg*8]);
        #pragma unroll
        for (int qt = 0; qt < 2; qt++)
          st[mt][qt] = __builtin_amdgcn_mfma_f32_16x16x32_bf16(kf, qf[qt][kk], st[mt][qt], 0, 0, 0);
      }
    }

    // online softmax per q-column (reduce across regs + lg groups)
    float nm[2], alpha[2];
    #pragma unroll
    for (int qt = 0; qt < 2; qt++){
      float mx = -1e30f;
      #pragma unroll
      for (int mt = 0; mt < 4; mt++)
        #pragma unroll
        for (int i = 0; i < 4; i++)
          mx = fmaxf(mx, st[mt][qt][i]);
      mx = fmaxf(mx, __shfl_xor(mx, 16));
      mx = fmaxf(mx, __shfl_xor(mx, 32));
      mx *= 0.125f;
      nm[qt] = fmaxf(mrow[qt], mx);
      alpha[qt] = __expf(mrow[qt] - nm[qt]);
      mrow[qt] = nm[qt];
    }
    #pragma unroll
    for (int qt = 0; qt < 2; qt++){
      float s = 0.f;
      #pragma unroll
      for (int mt = 0; mt < 4; mt++){
        short4v pb;
        #pragma unroll
        for (int i = 0; i < 4; i++){
          float e = __expf(st[mt][qt][i] * 0.125f - nm[qt]);
          s += e;
          pb[i] = f2bf(e);
        }
        *reinterpret_cast<short4v*>(&Pw[(qt*16 + lr)*LDP + mt*16 + lg*4]) = pb;
      }
      s += __shfl_xor(s, 16);
      s += __shfl_xor(s, 32);
      lsum[qt] = lsum[qt] * alpha[qt] + s;
    }
    // rescale O (O rows are q = qt*16 + lg*4 + i -> broadcast alpha from lane lg*4+i)
    #pragma unroll
    for (int qt = 0; qt < 2; qt++){
      float ab[4];
      #pragma unroll
      for (int i = 0; i < 4; i++) ab[i] = __shfl(alpha[qt], lg*4 + i);
      #pragma unroll
      for (int dt = 0; dt < 4; dt++)
        #pragma unroll
        for (int i = 0; i < 4; i++)
          o[qt][dt][i] *= ab[i];
    }
    asm volatile("s_waitcnt lgkmcnt(0)" ::: "memory");
    // PV: O[q][d] += P[q][kv] * V[kv][d]
    short8 pf[2][2];
    #pragma unroll
    for (int qt = 0; qt < 2; qt++)
      #pragma unroll
      for (int kk = 0; kk < 2; kk++)
        pf[qt][kk] = *reinterpret_cast<const short8*>(&Pw[(qt*16 + lr)*LDP + kk*32 + lg*8]);
    #pragma unroll
    for (int dt = 0; dt < 4; dt++){
      #pragma unroll
      for (int kk = 0; kk < 2; kk++){
        short8 vf = *reinterpret_cast<const short8*>(&Vlds[(dt*16 + lr)*LD + kk*32 + lg*8]);
        #pragma unroll
        for (int qt = 0; qt < 2; qt++)
          o[qt][dt] = __builtin_amdgcn_mfma_f32_16x16x32_bf16(pf[qt][kk], vf, o[qt][dt], 0, 0, 0);
      }
    }
  }

  #pragma unroll
  for (int qt = 0; qt < 2; qt++){
    float lb[4];
    #pragma unroll
    for (int i = 0; i < 4; i++) lb[i] = 1.0f / __shfl(lsum[qt], lg*4 + i);
    #pragma unroll
    for (int dt = 0; dt < 4; dt++){
      #pragma unroll
      for (int i = 0; i < 4; i++){
        const int q = q0 + w*32 + qt*16 + lg*4 + i;
        ctx[(size_t)(b*2048 + q) * 1024 + h*64 + dt*16 + lr] =
            __float2bfloat16(o[qt][dt][i] * lb[i]);
      }
    }
  }
}

extern "C" void kernel_launch(void* const* d_in, const int* in_sizes, int n_in,
                              void* d_out, int out_size, void* d_ws, size_t ws_size,
                              hipStream_t stream)
{
  const float* query = (const float*)d_in[0];
  const float* key   = (const float*)d_in[1];
  const float* value = (const float*)d_in[2];
  const float* Wq = (const float*)d_in[3];
  const float* bq = (const float*)d_in[4];
  const float* Wk = (const float*)d_in[5];
  const float* bk = (const float*)d_in[6];
  const float* Wv = (const float*)d_in[7];
  const float* bv = (const float*)d_in[8];
  const float* Wo = (const float*)d_in[9];
  const float* bo = (const float*)d_in[10];
  float* out = (float*)d_out;

  char* ws = (char*)d_ws;
  size_t off = 0;
  float* tab = (float*)(ws + off); off += (size_t)2048 * 32 * 2 * 4;   // cos/sin
  bf16*  Qa  = (bf16*)(ws + off);  off += (size_t)32 * 2048 * 64 * 2;  // [B*16,S,64]
  bf16*  Ka  = (bf16*)(ws + off);  off += (size_t)8 * 2048 * 64 * 2;   // [B*4,S,64]
  bf16*  Va  = (bf16*)(ws + off);  off += (size_t)8 * 64 * 2048 * 2;   // [B*4,64,S]
  bf16*  ctx = (bf16*)(ws + off);  off += (size_t)2 * 2048 * 1024 * 2; // [B,S,1024]

  rope_table_kernel<<<256, 256, 0, stream>>>(tab);
  gemm_q_kernel<<<dim3(8, 32), 256, 0, stream>>>(Qa, query, Wq, bq, tab);
  gemm_kv_kernel<<<dim3(2, 32, 2), 256, 0, stream>>>(Ka, Va, key, value, Wk, bk, Wv, bv, tab);
  attn_kernel<<<dim3(16, 32), 256, 0, stream>>>(ctx, Qa, Ka, Va);
  gemm_out_kernel<<<dim3(8, 32), 256, 0, stream>>>(out, ctx, Wo, bo);
}